// Round 11
// baseline (10351.619 us; speedup 1.0000x reference)
//
#include <hip/hip_runtime.h>
#include <math.h>

#define B_ 128
#define S_ 1024
#define F_ 256
#define H_ 256
#define G3 768
#define BGROUPS 4
#define NBLK 128
#define NTHR 64
#define H0_DEPTH 8
#define H1_DEPTH 2

// tagged h slab per (depth,bg): [nt(2)][pl(8)][hi(4)][jp(4)][col(16)] u64
//   element u64 = two tagged u32 (elems j=2jp, 2jp+1), u32 = (bf16<<16)|tag
//   h-index = pl*32 + hi*8 + j ; batch col = bg*32 + nt*16 + col
#define SLAB_U64 4096          // 32 KB
#define H0_U64 (H0_DEPTH * BGROUPS * SLAB_U64)
#define H1_U64 (H1_DEPTH * BGROUPS * SLAB_U64)
#define WS_ZERO_BYTES (4096 + (size_t)(H0_U64 + H1_U64) * 8)   // 1.28 MB

typedef __bf16 bf16x8 __attribute__((ext_vector_type(8)));
typedef float f32x4 __attribute__((ext_vector_type(4)));
typedef unsigned short us8 __attribute__((ext_vector_type(8)));
typedef unsigned long long u64;

__device__ __forceinline__ float sigf(float v) { return 1.0f / (1.0f + __expf(-v)); }
__device__ __forceinline__ float tanh_fast(float v) {
    return __builtin_fmaf(2.0f, sigf(2.0f * v), -1.0f);
}
__device__ __forceinline__ unsigned short f2bf(float f) {
    unsigned u = __builtin_bit_cast(unsigned, f);
    return (unsigned short)((u + 0x7fffu + ((u >> 16) & 1u)) >> 16);   // RNE
}
__device__ __forceinline__ f32x4 MF(bf16x8 a, bf16x8 b, f32x4 c) {
    return __builtin_amdgcn_mfma_f32_16x16x32_bf16(a, b, c, 0, 0, 0);
}
__device__ __forceinline__ u64 aload(const u64* p) {
    return __hip_atomic_load(p, __ATOMIC_RELAXED, __HIP_MEMORY_SCOPE_AGENT);
}
__device__ __forceinline__ void astore(u64* p, u64 v) {
    __hip_atomic_store(p, v, __ATOMIC_RELAXED, __HIP_MEMORY_SCOPE_AGENT);
}
__device__ __forceinline__ unsigned aload32(const unsigned* p) {
    return __hip_atomic_load(p, __ATOMIC_RELAXED, __HIP_MEMORY_SCOPE_AGENT);
}
__device__ __forceinline__ void astore32(unsigned* p, unsigned v) {
    __hip_atomic_store(p, v, __ATOMIC_RELAXED, __HIP_MEMORY_SCOPE_AGENT);
}

// coalesced per-wave slab read: 32 u64 loads; lanes stride 8B within 128B rows
__device__ __forceinline__ void loadq(const u64* rdb, u64* q) {
    #pragma unroll
    for (int pl = 0; pl < 8; ++pl)
        #pragma unroll
        for (int jp = 0; jp < 4; ++jp)
            q[pl * 4 + jp] = aload(rdb + pl * 256 + jp * 16);
}
__device__ __forceinline__ bool tagok(const u64* q, unsigned tag) {
    unsigned acc = 0;
    #pragma unroll
    for (int i = 0; i < 32; ++i) {
        acc |= ((unsigned)q[i] ^ tag) & 0xFFFFu;
        acc |= ((unsigned)(q[i] >> 32) ^ tag) & 0xFFFFu;
    }
    return acc == 0u;
}
__device__ __forceinline__ bf16x8 unpk(const u64* qq) {   // &q[pl*4]
    us8 u;
    u[0] = (unsigned short)(qq[0] >> 16); u[1] = (unsigned short)(qq[0] >> 48);
    u[2] = (unsigned short)(qq[1] >> 16); u[3] = (unsigned short)(qq[1] >> 48);
    u[4] = (unsigned short)(qq[2] >> 16); u[5] = (unsigned short)(qq[2] >> 48);
    u[6] = (unsigned short)(qq[3] >> 16); u[7] = (unsigned short)(qq[3] >> 48);
    return __builtin_bit_cast(bf16x8, u);
}

__global__ __launch_bounds__(NTHR, 1)
void lstm_w2(const float* __restrict__ x,    // (B,S,F)
             const float* __restrict__ fw,   // (F)
             const float* __restrict__ tw,   // (S)
             const float* __restrict__ Wih,  // (L,3H,F)
             const float* __restrict__ bih,  // (L,3H)
             const float* __restrict__ Whh,  // (L,3H,H)
             const float* __restrict__ bhh,  // (L,3H)
             float* __restrict__ out,        // outputs | hs | cs
             void* __restrict__ ws)
{
    __shared__ unsigned short sW[3 * 16 * 64 * 8];   // 48 KB, frag-ordered bf16

    unsigned* prog = (unsigned*)ws;                   // prog[(bg*2+nt)*16 + ug*2+uh]
    u64* h0buf = (u64*)((char*)ws + 4096);            // [8][bg] slabs
    u64* h1buf = h0buf + H0_U64;                      // [2][bg] slabs
    float* outputs = out;
    float* hs = out + (size_t)B_ * S_ * H_;
    float* cs = hs + (size_t)2 * B_ * H_;

    const int bid   = blockIdx.x;
    const int lane  = threadIdx.x;
    const int bgp   = bid & 1;
    const int nt    = (bid >> 1) & 1;
    const int uh    = (bid >> 2) & 1;
    const int ug    = (bid >> 3) & 7;
    const int layer = (bid >> 6) & 1;

    const float* Wih_l = Wih + (size_t)layer * G3 * F_;
    const float* Whh_l = Whh + (size_t)layer * G3 * H_;

    // ---- stage this wave's weights: 3 gates x 16 units x K=512 (fw folded) ----
    for (int idx = lane; idx < 3 * 16 * 64; idx += NTHR) {
        const int l  = idx & 63;
        const int kt = (idx >> 6) & 15;
        const int g  = idx >> 10;
        const int grow = g * H_ + ug * 32 + uh * 16 + (l & 15);
        const int k = kt * 32 + (l >> 4) * 8;
        float4 a, b;
        if (k < 256) {
            const float* s = Wih_l + (size_t)grow * F_ + k;
            a = *(const float4*)s; b = *(const float4*)(s + 4);
            if (layer == 0) {   // fold features_weighting into W_ih
                const float4 wa = *(const float4*)(fw + k);
                const float4 wb = *(const float4*)(fw + k + 4);
                a.x *= wa.x; a.y *= wa.y; a.z *= wa.z; a.w *= wa.w;
                b.x *= wb.x; b.y *= wb.y; b.z *= wb.z; b.w *= wb.w;
            }
        } else {
            const float* s = Whh_l + (size_t)grow * H_ + (k - 256);
            a = *(const float4*)s; b = *(const float4*)(s + 4);
        }
        us8 w;
        w[0] = f2bf(a.x); w[1] = f2bf(a.y); w[2] = f2bf(a.z); w[3] = f2bf(a.w);
        w[4] = f2bf(b.x); w[5] = f2bf(b.y); w[6] = f2bf(b.z); w[7] = f2bf(b.w);
        *(us8*)&sW[(size_t)idx * 8] = w;
    }
    __syncthreads();

    float bia[3][4];
    #pragma unroll
    for (int r = 0; r < 4; ++r) {
        const int gu = ug * 32 + uh * 16 + (lane >> 4) * 4 + r;
        #pragma unroll
        for (int s = 0; s < 3; ++s)
            bia[s][r] = bih[layer * G3 + s * H_ + gu] + bhh[layer * G3 + s * H_ + gu];
    }

    const int ul0 = uh * 16 + (lane >> 4) * 4;        // unit base (mult of 4)
    const int hg0 = ug * 32 + ul0;
    const size_t wofs = (size_t)nt * 2048 + (size_t)ug * 256
                      + (size_t)(uh * 2 + ((lane >> 4) >> 1)) * 64
                      + (size_t)(((lane >> 4) & 1) * 2) * 16 + (lane & 15);
    const size_t rofs = (size_t)nt * 2048 + (size_t)(lane >> 4) * 64 + (lane & 15);

    int bg[2], bcol[2], dom[2];
    #pragma unroll
    for (int c = 0; c < 2; ++c) {
        bg[c]   = bgp * 2 + c;
        bcol[c] = bg[c] * 32 + nt * 16 + (lane & 15);
        dom[c]  = bg[c] * 2 + nt;
    }

    float c_reg[2][4] = {{0.f,0.f,0.f,0.f},{0.f,0.f,0.f,0.f}};

    #define WAf(g, kt) (*(const bf16x8*)&sW[(size_t)(((g) * 16 + (kt)) * 64 + lane) * 8])

    if (layer == 0) {
        float4 xr[2][16];
        u64 q[2][32];
        // prologue: per chain issue x(0) then h0(-1) polls (slab 7, tag 0)
        #pragma unroll
        for (int c = 0; c < 2; ++c) {
            #pragma unroll
            for (int kt = 0; kt < 8; ++kt) {
                const float* s = x + ((size_t)bcol[c] * S_) * F_ + kt * 32 + (lane >> 4) * 8;
                xr[c][2 * kt] = *(const float4*)s;
                xr[c][2 * kt + 1] = *(const float4*)(s + 4);
            }
            loadq(h0buf + (size_t)(7 * BGROUPS + bg[c]) * SLAB_U64 + rofs, q[c]);
        }

        for (int p = 0; p < S_; ++p) {
            const float twc = tw[p];
            #pragma unroll
            for (int c = 0; c < 2; ++c) {
                // convert x(p) (forces counted wait on this chain's x only)
                bf16x8 xb[8];
                #pragma unroll
                for (int kt = 0; kt < 8; ++kt) {
                    const float4 a = xr[c][2 * kt], b = xr[c][2 * kt + 1];
                    us8 w;
                    w[0] = f2bf(a.x); w[1] = f2bf(a.y); w[2] = f2bf(a.z); w[3] = f2bf(a.w);
                    w[4] = f2bf(b.x); w[5] = f2bf(b.y); w[6] = f2bf(b.z); w[7] = f2bf(b.w);
                    xb[kt] = __builtin_bit_cast(bf16x8, w);
                }
                f32x4 ai = {0.f, 0.f, 0.f, 0.f}, ag = ai, ao = ai;
                #pragma unroll
                for (int kt = 0; kt < 8; ++kt) {      // x-half while h polls fly
                    ai = MF(WAf(0, kt), xb[kt], ai);
                    ag = MF(WAf(1, kt), xb[kt], ag);
                    ao = MF(WAf(2, kt), xb[kt], ao);
                }
                #pragma unroll
                for (int r = 0; r < 4; ++r) { ai[r] *= twc; ag[r] *= twc; ao[r] *= twc; }

                const u64* rdb = h0buf
                    + (size_t)(((p - 1) & 7) * BGROUPS + bg[c]) * SLAB_U64 + rofs;
                while (!__all(tagok(q[c], (unsigned)p))) {
                    __builtin_amdgcn_s_sleep(1);
                    loadq(rdb, q[c]);
                }
                #pragma unroll
                for (int pl = 0; pl < 8; ++pl) {
                    const bf16x8 hb = unpk(&q[c][pl * 4]);
                    ai = MF(WAf(0, 8 + pl), hb, ai);
                    ag = MF(WAf(1, 8 + pl), hb, ag);
                    ao = MF(WAf(2, 8 + pl), hb, ao);
                }

                // back-pressure: overwriting slab p&7 (tag p-7) needs layer1 >= p-7
                if (p >= H0_DEPTH) {
                    const unsigned need = (unsigned)(p - (H0_DEPTH - 1));
                    bool ok;
                    do {
                        const unsigned pv = (lane < 16)
                            ? aload32(&prog[dom[c] * 16 + lane]) : need;
                        ok = __all((int)(pv >= need));
                    } while (!ok);
                }

                u64* wb = h0buf + (size_t)((p & 7) * BGROUPS + bg[c]) * SLAB_U64 + wofs;
                const unsigned tagv = (unsigned)(p + 1);
                float hnv[4], cnv[4];
                unsigned er[4];
                #pragma unroll
                for (int r = 0; r < 4; ++r) {
                    const float gi = ai[r] + bia[0][r];
                    const float gg = ag[r] + bia[1][r];
                    const float go = ao[r] + bia[2][r];
                    const float cp = c_reg[c][r];
                    const float fg = sigf(cp);             // forget = sigmoid(c_prev)
                    const float cn = fg * cp + sigf(gi) * tanh_fast(gg);
                    const float hn = sigf(go) * tanh_fast(cn);
                    c_reg[c][r] = cn; hnv[r] = hn; cnv[r] = cn;
                    er[r] = ((unsigned)f2bf(hn) << 16) | tagv;
                }
                astore(wb,      er[0] | ((u64)er[1] << 32));
                astore(wb + 16, er[2] | ((u64)er[3] << 32));

                if (p == S_ - 1) {
                    *(float4*)(hs + (size_t)bcol[c] * H_ + hg0) =
                        make_float4(hnv[0], hnv[1], hnv[2], hnv[3]);
                    *(float4*)(cs + (size_t)bcol[c] * H_ + hg0) =
                        make_float4(cnv[0], cnv[1], cnv[2], cnv[3]);
                } else {
                    // issue next-phase loads: x(p+1) first, then h0(p) polls
                    #pragma unroll
                    for (int kt = 0; kt < 8; ++kt) {
                        const float* s = x + ((size_t)bcol[c] * S_ + (p + 1)) * F_
                                       + kt * 32 + (lane >> 4) * 8;
                        xr[c][2 * kt] = *(const float4*)s;
                        xr[c][2 * kt + 1] = *(const float4*)(s + 4);
                    }
                    loadq(h0buf + (size_t)((p & 7) * BGROUPS + bg[c]) * SLAB_U64 + rofs,
                          q[c]);
                }
            }
        }
    } else {
        u64 q0[2][32], q1[2][32];
        // prologue p=1: q0 <- h0 slab 0 (tag 1); q1 <- h1 slab 1 (tag 0, zeroed)
        #pragma unroll
        for (int c = 0; c < 2; ++c) {
            loadq(h0buf + (size_t)(0 * BGROUPS + bg[c]) * SLAB_U64 + rofs, q0[c]);
            loadq(h1buf + (size_t)(1 * BGROUPS + bg[c]) * SLAB_U64 + rofs, q1[c]);
        }

        for (int p = 1; p <= S_; ++p) {
            const int t = p - 1;
            #pragma unroll
            for (int c = 0; c < 2; ++c) {
                const u64* rd0 = h0buf
                    + (size_t)(((p - 1) & 7) * BGROUPS + bg[c]) * SLAB_U64 + rofs;
                while (!__all(tagok(q0[c], (unsigned)p))) {
                    __builtin_amdgcn_s_sleep(1);
                    loadq(rd0, q0[c]);
                }
                if (lane == 0)                 // publish h0(p-1) consumption
                    astore32(&prog[dom[c] * 16 + ug * 2 + uh], (unsigned)p);

                f32x4 ai = {0.f, 0.f, 0.f, 0.f}, ag = ai, ao = ai;
                #pragma unroll
                for (int pl = 0; pl < 8; ++pl) {
                    const bf16x8 hb = unpk(&q0[c][pl * 4]);
                    ai = MF(WAf(0, pl), hb, ai);
                    ag = MF(WAf(1, pl), hb, ag);
                    ao = MF(WAf(2, pl), hb, ao);
                }

                const u64* rd1 = h1buf
                    + (size_t)(((p - 2) & 1) * BGROUPS + bg[c]) * SLAB_U64 + rofs;
                while (!__all(tagok(q1[c], (unsigned)(p - 1)))) {
                    __builtin_amdgcn_s_sleep(1);
                    loadq(rd1, q1[c]);
                }
                #pragma unroll
                for (int pl = 0; pl < 8; ++pl) {
                    const bf16x8 hb = unpk(&q1[c][pl * 4]);
                    ai = MF(WAf(0, 8 + pl), hb, ai);
                    ag = MF(WAf(1, 8 + pl), hb, ag);
                    ao = MF(WAf(2, 8 + pl), hb, ao);
                }

                u64* wb = h1buf
                    + (size_t)(((p - 1) & 1) * BGROUPS + bg[c]) * SLAB_U64 + wofs;
                const unsigned tagv = (unsigned)p;
                float hnv[4], cnv[4];
                unsigned er[4];
                #pragma unroll
                for (int r = 0; r < 4; ++r) {
                    const float gi = ai[r] + bia[0][r];
                    const float gg = ag[r] + bia[1][r];
                    const float go = ao[r] + bia[2][r];
                    const float cp = c_reg[c][r];
                    const float fg = sigf(cp);             // forget = sigmoid(c_prev)
                    const float cn = fg * cp + sigf(gi) * tanh_fast(gg);
                    const float hn = sigf(go) * tanh_fast(cn);
                    c_reg[c][r] = cn; hnv[r] = hn; cnv[r] = cn;
                    er[r] = ((unsigned)f2bf(hn) << 16) | tagv;
                }
                astore(wb,      er[0] | ((u64)er[1] << 32));
                astore(wb + 16, er[2] | ((u64)er[3] << 32));

                *(float4*)(outputs + ((size_t)bcol[c] * S_ + t) * H_ + hg0) =
                    make_float4(hnv[0], hnv[1], hnv[2], hnv[3]);
                if (p == S_) {
                    *(float4*)(hs + (size_t)B_ * H_ + (size_t)bcol[c] * H_ + hg0) =
                        make_float4(hnv[0], hnv[1], hnv[2], hnv[3]);
                    *(float4*)(cs + (size_t)B_ * H_ + (size_t)bcol[c] * H_ + hg0) =
                        make_float4(cnv[0], cnv[1], cnv[2], cnv[3]);
                } else {
                    // issue next-phase polls: h0(p) slab p&7 (tag p+1),
                    // h1(p-1) slab (p-1)&1 (tag p, just written by domain)
                    loadq(h0buf + (size_t)((p & 7) * BGROUPS + bg[c]) * SLAB_U64 + rofs,
                          q0[c]);
                    loadq(h1buf + (size_t)(((p - 1) & 1) * BGROUPS + bg[c]) * SLAB_U64 + rofs,
                          q1[c]);
                }
            }
        }
    }
}

extern "C" void kernel_launch(void* const* d_in, const int* in_sizes, int n_in,
                              void* d_out, int out_size, void* d_ws, size_t ws_size,
                              hipStream_t stream) {
    const float* x   = (const float*)d_in[0];
    const float* fw  = (const float*)d_in[1];
    const float* tw  = (const float*)d_in[2];
    const float* Wih = (const float*)d_in[3];
    const float* bih = (const float*)d_in[4];
    const float* Whh = (const float*)d_in[5];
    const float* bhh = (const float*)d_in[6];
    float* out = (float*)d_out;

    // zero prog + tagged slabs each call (tag 0 == valid h(-1)=0); 1.28 MB
    hipMemsetAsync(d_ws, 0, WS_ZERO_BYTES, stream);

    void* kargs[] = { (void*)&x, (void*)&fw, (void*)&tw, (void*)&Wih, (void*)&bih,
                      (void*)&Whh, (void*)&bhh, (void*)&out, (void*)&d_ws };
    hipError_t e = hipLaunchCooperativeKernel((const void*)lstm_w2,
                                              dim3(NBLK), dim3(NTHR),
                                              kargs, 0, stream);
    if (e != hipSuccess) {
        // fallback: plain launch; 128 blocks x 48KB LDS x 64 thr on 256 CUs are
        // trivially co-resident; only device-scope atomics used.
        lstm_w2<<<dim3(NBLK), dim3(NTHR), 0, stream>>>(
            x, fw, tw, Wih, bih, Whh, bhh, out, d_ws);
    }
}

// Round 12
// 8811.287 us; speedup vs baseline: 1.1748x; 1.1748x over previous
//
#include <hip/hip_runtime.h>
#include <math.h>

#define B_ 128
#define S_ 1024
#define F_ 256
#define H_ 256
#define G3 768
#define BGROUPS 4
#define NBLK 256
#define NTHR 64
#define H0_DEPTH 32
#define H1_DEPTH 2

// tagged h slab per (depth,bg): [nt(2)][pl(8)][hi(4)][jp(4)][col(16)] u64
//   element u64 = two tagged u32 (elems j=2jp, 2jp+1), u32 = (bf16<<16)|tag
//   h-index = pl*32 + hi*8 + j ; batch col = bg*32 + nt*16 + col
#define SLAB_U64 4096          // 32 KB
#define H0_U64 (H0_DEPTH * BGROUPS * SLAB_U64)
#define H1_U64 (H1_DEPTH * BGROUPS * SLAB_U64)
#define WS_ZERO_BYTES (4096 + (size_t)(H0_U64 + H1_U64) * 8)   // ~4.5 MB

typedef __bf16 bf16x8 __attribute__((ext_vector_type(8)));
typedef float f32x4 __attribute__((ext_vector_type(4)));
typedef unsigned short us8 __attribute__((ext_vector_type(8)));
typedef unsigned long long u64;

__device__ __forceinline__ float sigf(float v) { return 1.0f / (1.0f + __expf(-v)); }
__device__ __forceinline__ float tanh_fast(float v) {
    return __builtin_fmaf(2.0f, sigf(2.0f * v), -1.0f);
}
__device__ __forceinline__ unsigned short f2bf(float f) {
    unsigned u = __builtin_bit_cast(unsigned, f);
    return (unsigned short)((u + 0x7fffu + ((u >> 16) & 1u)) >> 16);   // RNE
}
__device__ __forceinline__ f32x4 MF(bf16x8 a, bf16x8 b, f32x4 c) {
    return __builtin_amdgcn_mfma_f32_16x16x32_bf16(a, b, c, 0, 0, 0);
}
__device__ __forceinline__ u64 aload(const u64* p) {
    return __hip_atomic_load(p, __ATOMIC_RELAXED, __HIP_MEMORY_SCOPE_AGENT);
}
__device__ __forceinline__ void astore(u64* p, u64 v) {
    __hip_atomic_store(p, v, __ATOMIC_RELAXED, __HIP_MEMORY_SCOPE_AGENT);
}
__device__ __forceinline__ unsigned aload32(const unsigned* p) {
    return __hip_atomic_load(p, __ATOMIC_RELAXED, __HIP_MEMORY_SCOPE_AGENT);
}
__device__ __forceinline__ void astore32(unsigned* p, unsigned v) {
    __hip_atomic_store(p, v, __ATOMIC_RELAXED, __HIP_MEMORY_SCOPE_AGENT);
}

// coalesced per-wave slab read: 32 u64 loads; lanes stride 8B within 128B rows
__device__ __forceinline__ void loadq(const u64* rdb, u64* q) {
    #pragma unroll
    for (int pl = 0; pl < 8; ++pl)
        #pragma unroll
        for (int jp = 0; jp < 4; ++jp)
            q[pl * 4 + jp] = aload(rdb + pl * 256 + jp * 16);
}
__device__ __forceinline__ bool tagok(const u64* q, unsigned tag) {
    unsigned acc = 0;
    #pragma unroll
    for (int i = 0; i < 32; ++i) {
        acc |= ((unsigned)q[i] ^ tag) & 0xFFFFu;
        acc |= ((unsigned)(q[i] >> 32) ^ tag) & 0xFFFFu;
    }
    return acc == 0u;
}
__device__ __forceinline__ bf16x8 unpk(const u64* qq) {   // &q[pl*4]
    us8 u;
    u[0] = (unsigned short)(qq[0] >> 16); u[1] = (unsigned short)(qq[0] >> 48);
    u[2] = (unsigned short)(qq[1] >> 16); u[3] = (unsigned short)(qq[1] >> 48);
    u[4] = (unsigned short)(qq[2] >> 16); u[5] = (unsigned short)(qq[2] >> 48);
    u[6] = (unsigned short)(qq[3] >> 16); u[7] = (unsigned short)(qq[3] >> 48);
    return __builtin_bit_cast(bf16x8, u);
}

__global__ __launch_bounds__(NTHR)
void lstm_w3(const float* __restrict__ x,    // (B,S,F)
             const float* __restrict__ fw,   // (F)
             const float* __restrict__ tw,   // (S)
             const float* __restrict__ Wih,  // (L,3H,F)
             const float* __restrict__ bih,  // (L,3H)
             const float* __restrict__ Whh,  // (L,3H,H)
             const float* __restrict__ bhh,  // (L,3H)
             float* __restrict__ out,        // outputs | hs | cs
             void* __restrict__ ws)
{
    __shared__ unsigned short sW[3 * 16 * 64 * 8];   // 48 KB, frag-ordered bf16

    unsigned* prog = (unsigned*)ws;                   // prog[(bg*2+nt)*16 + ug*2+uh]
    u64* h0buf = (u64*)((char*)ws + 4096);            // [32][bg] slabs
    u64* h1buf = h0buf + H0_U64;                      // [2][bg] slabs
    float* outputs = out;
    float* hs = out + (size_t)B_ * S_ * H_;
    float* cs = hs + (size_t)2 * B_ * H_;

    const int bid   = blockIdx.x;
    const int lane  = threadIdx.x;
    const int ntw   = bid & 1;
    const int uh    = (bid >> 1) & 1;
    const int bg    = (bid >> 2) & 3;
    const int ug    = (bid >> 4) & 7;
    const int layer = (bid >> 7) & 1;

    const float* Wih_l = Wih + (size_t)layer * G3 * F_;
    const float* Whh_l = Whh + (size_t)layer * G3 * H_;

    // ---- stage this wave's weights: 3 gates x 16 units x K=512 (fw folded) ----
    // A-frag (16x16x32): lane holds A[(l&15)][(l>>4)*8 + j] of tile (gate,kt)
    for (int idx = lane; idx < 3 * 16 * 64; idx += NTHR) {
        const int l  = idx & 63;
        const int kt = (idx >> 6) & 15;
        const int g  = idx >> 10;
        const int grow = g * H_ + ug * 32 + uh * 16 + (l & 15);
        const int k = kt * 32 + (l >> 4) * 8;
        float4 a, b;
        if (k < 256) {
            const float* s = Wih_l + (size_t)grow * F_ + k;
            a = *(const float4*)s; b = *(const float4*)(s + 4);
            if (layer == 0) {   // fold features_weighting into W_ih
                const float4 wa = *(const float4*)(fw + k);
                const float4 wb = *(const float4*)(fw + k + 4);
                a.x *= wa.x; a.y *= wa.y; a.z *= wa.z; a.w *= wa.w;
                b.x *= wb.x; b.y *= wb.y; b.z *= wb.z; b.w *= wb.w;
            }
        } else {
            const float* s = Whh_l + (size_t)grow * H_ + (k - 256);
            a = *(const float4*)s; b = *(const float4*)(s + 4);
        }
        us8 w;
        w[0] = f2bf(a.x); w[1] = f2bf(a.y); w[2] = f2bf(a.z); w[3] = f2bf(a.w);
        w[4] = f2bf(b.x); w[5] = f2bf(b.y); w[6] = f2bf(b.z); w[7] = f2bf(b.w);
        *(us8*)&sW[(size_t)idx * 8] = w;
    }
    __syncthreads();

    float bia[3][4];
    #pragma unroll
    for (int r = 0; r < 4; ++r) {
        const int gu = ug * 32 + uh * 16 + (lane >> 4) * 4 + r;
        #pragma unroll
        for (int s = 0; s < 3; ++s)
            bia[s][r] = bih[layer * G3 + s * H_ + gu] + bhh[layer * G3 + s * H_ + gu];
    }

    const int ul0  = uh * 16 + (lane >> 4) * 4;       // unit base (mult of 4)
    const int hg0  = ug * 32 + ul0;
    const int bcol = bg * 32 + ntw * 16 + (lane & 15);
    const size_t wofs = (size_t)ntw * 2048 + (size_t)ug * 256
                      + (size_t)(uh * 2 + ((lane >> 4) >> 1)) * 64
                      + (size_t)(((lane >> 4) & 1) * 2) * 16 + (lane & 15);
    const size_t rofs = (size_t)ntw * 2048 + (size_t)(lane >> 4) * 64 + (lane & 15);
    const int dom = bg * 2 + ntw;                     // sync domain (bg, nt)

    float c_reg[4] = {0.f, 0.f, 0.f, 0.f};

    #define WAf(g, kt) (*(const bf16x8*)&sW[(size_t)(((g) * 16 + (kt)) * 64 + lane) * 8])

    if (layer == 0) {
        float4 xr[16];
        u64 q[32];
        f32x4 ai, ag, ao;

        // ---- prologue: x(0) -> acc (x-half), issue x(1), issue h0(-1) polls ----
        #pragma unroll
        for (int kt = 0; kt < 8; ++kt) {
            const float* s = x + ((size_t)bcol * S_) * F_ + kt * 32 + (lane >> 4) * 8;
            xr[2 * kt] = *(const float4*)s; xr[2 * kt + 1] = *(const float4*)(s + 4);
        }
        {
            bf16x8 xb[8];
            #pragma unroll
            for (int kt = 0; kt < 8; ++kt) {
                const float4 a = xr[2 * kt], b = xr[2 * kt + 1];
                us8 w;
                w[0] = f2bf(a.x); w[1] = f2bf(a.y); w[2] = f2bf(a.z); w[3] = f2bf(a.w);
                w[4] = f2bf(b.x); w[5] = f2bf(b.y); w[6] = f2bf(b.z); w[7] = f2bf(b.w);
                xb[kt] = __builtin_bit_cast(bf16x8, w);
            }
            ai = f32x4{0.f,0.f,0.f,0.f}; ag = ai; ao = ai;
            #pragma unroll
            for (int kt = 0; kt < 8; ++kt) {
                ai = MF(WAf(0, kt), xb[kt], ai);
                ag = MF(WAf(1, kt), xb[kt], ag);
                ao = MF(WAf(2, kt), xb[kt], ao);
            }
            const float twc = tw[0];
            #pragma unroll
            for (int r = 0; r < 4; ++r) { ai[r] *= twc; ag[r] *= twc; ao[r] *= twc; }
        }
        #pragma unroll
        for (int kt = 0; kt < 8; ++kt) {   // issue x(1)
            const float* s = x + ((size_t)bcol * S_ + 1) * F_ + kt * 32 + (lane >> 4) * 8;
            xr[2 * kt] = *(const float4*)s; xr[2 * kt + 1] = *(const float4*)(s + 4);
        }
        loadq(h0buf + (size_t)((H0_DEPTH - 1) * BGROUPS + bg) * SLAB_U64 + rofs, q);

        unsigned prog_min = 0;             // cached wave-min of consumer progress

        for (int p = 0; p < S_; ++p) {
            // ---- check h0(p-1) polls (tag p) ----
            const u64* rdb = h0buf
                + (size_t)((((p - 1) & (H0_DEPTH - 1)) * BGROUPS) + bg) * SLAB_U64 + rofs;
            while (!__all(tagok(q, (unsigned)p))) loadq(rdb, q);

            #pragma unroll
            for (int pl = 0; pl < 8; ++pl) {
                const bf16x8 hb = unpk(&q[pl * 4]);
                ai = MF(WAf(0, 8 + pl), hb, ai);
                ag = MF(WAf(1, 8 + pl), hb, ag);
                ao = MF(WAf(2, 8 + pl), hb, ao);
            }

            // ---- back-pressure (cached; re-read only when cache lacks slack) ----
            if (p >= H0_DEPTH && prog_min < (unsigned)(p - (H0_DEPTH - 1))) {
                const unsigned need = (unsigned)(p - (H0_DEPTH - 1));
                unsigned mv;
                do {
                    unsigned pv = (lane < 16)
                        ? aload32(&prog[dom * 16 + lane]) : 0xFFFFFFFFu;
                    #pragma unroll
                    for (int o = 1; o < 16; o <<= 1)
                        pv = min(pv, (unsigned)__shfl_xor((int)pv, o));
                    mv = (unsigned)__shfl((int)pv, 0);
                } while (mv < need);
                prog_min = mv;
            }

            // ---- update + tagged store h0(p) ----
            u64* wb = h0buf
                + (size_t)(((p & (H0_DEPTH - 1)) * BGROUPS) + bg) * SLAB_U64 + wofs;
            const unsigned tagv = (unsigned)(p + 1);
            float hnv[4], cnv[4];
            unsigned er[4];
            #pragma unroll
            for (int r = 0; r < 4; ++r) {
                const float gi = ai[r] + bia[0][r];
                const float gg = ag[r] + bia[1][r];
                const float go = ao[r] + bia[2][r];
                const float cp = c_reg[r];
                const float fg = sigf(cp);                 // forget = sigmoid(c_prev)
                const float cn = fg * cp + sigf(gi) * tanh_fast(gg);
                const float hn = sigf(go) * tanh_fast(cn);
                c_reg[r] = cn; hnv[r] = hn; cnv[r] = cn;
                er[r] = ((unsigned)f2bf(hn) << 16) | tagv;
            }
            astore(wb,      er[0] | ((u64)er[1] << 32));
            astore(wb + 16, er[2] | ((u64)er[3] << 32));

            if (p == S_ - 1) {
                *(float4*)(hs + (size_t)bcol * H_ + hg0) =
                    make_float4(hnv[0], hnv[1], hnv[2], hnv[3]);
                *(float4*)(cs + (size_t)bcol * H_ + hg0) =
                    make_float4(cnv[0], cnv[1], cnv[2], cnv[3]);
            } else {
                // ---- gap filler: convert x(p+1), x-half MFMAs, issue x(p+2),
                //      THEN issue h0(p) polls (samples well after peer stores) ----
                bf16x8 xb[8];
                #pragma unroll
                for (int kt = 0; kt < 8; ++kt) {
                    const float4 a = xr[2 * kt], b = xr[2 * kt + 1];
                    us8 w;
                    w[0] = f2bf(a.x); w[1] = f2bf(a.y); w[2] = f2bf(a.z); w[3] = f2bf(a.w);
                    w[4] = f2bf(b.x); w[5] = f2bf(b.y); w[6] = f2bf(b.z); w[7] = f2bf(b.w);
                    xb[kt] = __builtin_bit_cast(bf16x8, w);
                }
                ai = f32x4{0.f,0.f,0.f,0.f}; ag = ai; ao = ai;
                #pragma unroll
                for (int kt = 0; kt < 8; ++kt) {
                    ai = MF(WAf(0, kt), xb[kt], ai);
                    ag = MF(WAf(1, kt), xb[kt], ag);
                    ao = MF(WAf(2, kt), xb[kt], ao);
                }
                const float twc = tw[p + 1];
                #pragma unroll
                for (int r = 0; r < 4; ++r) { ai[r] *= twc; ag[r] *= twc; ao[r] *= twc; }
                if (p + 2 < S_) {
                    #pragma unroll
                    for (int kt = 0; kt < 8; ++kt) {
                        const float* s = x + ((size_t)bcol * S_ + (p + 2)) * F_
                                       + kt * 32 + (lane >> 4) * 8;
                        xr[2 * kt] = *(const float4*)s;
                        xr[2 * kt + 1] = *(const float4*)(s + 4);
                    }
                }
                loadq(h0buf + (size_t)(((p & (H0_DEPTH - 1)) * BGROUPS) + bg) * SLAB_U64
                      + rofs, q);
            }
        }
    } else {
        u64 q0[32], q1[32];
        // prologue p=1: q0 <- h0 slab 0 (tag 1); q1 <- h1 slab 1 (tag 0, zeroed)
        loadq(h0buf + (size_t)(0 * BGROUPS + bg) * SLAB_U64 + rofs, q0);
        loadq(h1buf + (size_t)(1 * BGROUPS + bg) * SLAB_U64 + rofs, q1);

        for (int p = 1; p <= S_; ++p) {
            const int t = p - 1;
            const u64* rd0 = h0buf
                + (size_t)((((p - 1) & (H0_DEPTH - 1)) * BGROUPS) + bg) * SLAB_U64 + rofs;
            while (!__all(tagok(q0, (unsigned)p))) loadq(rd0, q0);
            if (lane == 0)                 // publish h0(p-1) consumption
                astore32(&prog[dom * 16 + ug * 2 + uh], (unsigned)p);

            f32x4 ai = {0.f, 0.f, 0.f, 0.f}, ag = ai, ao = ai;
            #pragma unroll
            for (int pl = 0; pl < 8; ++pl) {
                const bf16x8 hb = unpk(&q0[pl * 4]);
                ai = MF(WAf(0, pl), hb, ai);
                ag = MF(WAf(1, pl), hb, ag);
                ao = MF(WAf(2, pl), hb, ao);
            }

            const u64* rd1 = h1buf
                + (size_t)((((p - 2) & 1) * BGROUPS) + bg) * SLAB_U64 + rofs;
            while (!__all(tagok(q1, (unsigned)(p - 1)))) loadq(rd1, q1);
            #pragma unroll
            for (int pl = 0; pl < 8; ++pl) {
                const bf16x8 hb = unpk(&q1[pl * 4]);
                ai = MF(WAf(0, 8 + pl), hb, ai);
                ag = MF(WAf(1, 8 + pl), hb, ag);
                ao = MF(WAf(2, 8 + pl), hb, ao);
            }

            u64* wb = h1buf
                + (size_t)((((p - 1) & 1) * BGROUPS) + bg) * SLAB_U64 + wofs;
            const unsigned tagv = (unsigned)p;
            float hnv[4], cnv[4];
            unsigned er[4];
            #pragma unroll
            for (int r = 0; r < 4; ++r) {
                const float gi = ai[r] + bia[0][r];
                const float gg = ag[r] + bia[1][r];
                const float go = ao[r] + bia[2][r];
                const float cp = c_reg[r];
                const float fg = sigf(cp);                 // forget = sigmoid(c_prev)
                const float cn = fg * cp + sigf(gi) * tanh_fast(gg);
                const float hn = sigf(go) * tanh_fast(cn);
                c_reg[r] = cn; hnv[r] = hn; cnv[r] = cn;
                er[r] = ((unsigned)f2bf(hn) << 16) | tagv;
            }
            astore(wb,      er[0] | ((u64)er[1] << 32));
            astore(wb + 16, er[2] | ((u64)er[3] << 32));

            *(float4*)(outputs + ((size_t)bcol * S_ + t) * H_ + hg0) =
                make_float4(hnv[0], hnv[1], hnv[2], hnv[3]);
            if (p == S_) {
                *(float4*)(hs + (size_t)B_ * H_ + (size_t)bcol * H_ + hg0) =
                    make_float4(hnv[0], hnv[1], hnv[2], hnv[3]);
                *(float4*)(cs + (size_t)B_ * H_ + (size_t)bcol * H_ + hg0) =
                    make_float4(cnv[0], cnv[1], cnv[2], cnv[3]);
            } else {
                // issue next-phase polls: h0(p) (tag p+1), h1(p-1) (tag p)
                loadq(h0buf + (size_t)(((p & (H0_DEPTH - 1)) * BGROUPS) + bg) * SLAB_U64
                      + rofs, q0);
                loadq(h1buf + (size_t)((((p - 1) & 1) * BGROUPS) + bg) * SLAB_U64
                      + rofs, q1);
            }
        }
    }
}

extern "C" void kernel_launch(void* const* d_in, const int* in_sizes, int n_in,
                              void* d_out, int out_size, void* d_ws, size_t ws_size,
                              hipStream_t stream) {
    const float* x   = (const float*)d_in[0];
    const float* fw  = (const float*)d_in[1];
    const float* tw  = (const float*)d_in[2];
    const float* Wih = (const float*)d_in[3];
    const float* bih = (const float*)d_in[4];
    const float* Whh = (const float*)d_in[5];
    const float* bhh = (const float*)d_in[6];
    float* out = (float*)d_out;

    // zero prog + tagged slabs each call (tag 0 == valid h(-1)=0); ~4.5 MB
    hipMemsetAsync(d_ws, 0, WS_ZERO_BYTES, stream);

    void* kargs[] = { (void*)&x, (void*)&fw, (void*)&tw, (void*)&Wih, (void*)&bih,
                      (void*)&Whh, (void*)&bhh, (void*)&out, (void*)&d_ws };
    hipError_t e = hipLaunchCooperativeKernel((const void*)lstm_w3,
                                              dim3(NBLK), dim3(NTHR),
                                              kargs, 0, stream);
    if (e != hipSuccess) {
        // fallback: plain launch; 256 blocks x 48KB LDS x 64 thr -> >=1/CU on
        // 256 CUs, trivially co-resident; only device-scope atomics used.
        lstm_w3<<<dim3(NBLK), dim3(NTHR), 0, stream>>>(
            x, fw, tw, Wih, bih, Whh, bhh, out, d_ws);
    }
}

// Round 13
// 3833.856 us; speedup vs baseline: 2.7001x; 2.2983x over previous
//
#include <hip/hip_runtime.h>
#include <math.h>

#define B_ 128
#define S_ 1024
#define F_ 256
#define H_ 256
#define G3 768
#define BGROUPS 4
#define NBLK 256
#define NTHR 64
#define H0_DEPTH 8
#define H1_DEPTH 2

// tagged h slab per (depth,bg): [nt(2)][pl(8)][hi(4)][jp(4)][col(16)] u64
//   element u64 = two tagged u32 (elems j=2jp, 2jp+1), u32 = (bf16<<16)|tag
//   h-index = pl*32 + hi*8 + j ; batch col = bg*32 + nt*16 + col
#define SLAB_U64 4096          // 32 KB
#define H0_U64 (H0_DEPTH * BGROUPS * SLAB_U64)
#define H1_U64 (H1_DEPTH * BGROUPS * SLAB_U64)
#define WS_ZERO_BYTES (4096 + (size_t)(H0_U64 + H1_U64) * 8)   // 1.28 MB

typedef __bf16 bf16x8 __attribute__((ext_vector_type(8)));
typedef float f32x4 __attribute__((ext_vector_type(4)));
typedef unsigned short us8 __attribute__((ext_vector_type(8)));
typedef unsigned long long u64;

__device__ __forceinline__ float sigf(float v) { return 1.0f / (1.0f + __expf(-v)); }
__device__ __forceinline__ float tanh_fast(float v) {
    return __builtin_fmaf(2.0f, sigf(2.0f * v), -1.0f);
}
__device__ __forceinline__ unsigned short f2bf(float f) {
    unsigned u = __builtin_bit_cast(unsigned, f);
    return (unsigned short)((u + 0x7fffu + ((u >> 16) & 1u)) >> 16);   // RNE
}
__device__ __forceinline__ f32x4 MF(bf16x8 a, bf16x8 b, f32x4 c) {
    return __builtin_amdgcn_mfma_f32_16x16x32_bf16(a, b, c, 0, 0, 0);
}
__device__ __forceinline__ u64 aload(const u64* p) {
    return __hip_atomic_load(p, __ATOMIC_RELAXED, __HIP_MEMORY_SCOPE_AGENT);
}
__device__ __forceinline__ void astore(u64* p, u64 v) {
    __hip_atomic_store(p, v, __ATOMIC_RELAXED, __HIP_MEMORY_SCOPE_AGENT);
}
__device__ __forceinline__ unsigned aload32(const unsigned* p) {
    return __hip_atomic_load(p, __ATOMIC_RELAXED, __HIP_MEMORY_SCOPE_AGENT);
}
__device__ __forceinline__ void astore32(unsigned* p, unsigned v) {
    __hip_atomic_store(p, v, __ATOMIC_RELAXED, __HIP_MEMORY_SCOPE_AGENT);
}

// coalesced per-wave slab read: 32 u64 loads; lanes stride 8B within 128B rows
__device__ __forceinline__ void loadq(const u64* rdb, u64* q) {
    #pragma unroll
    for (int pl = 0; pl < 8; ++pl)
        #pragma unroll
        for (int jp = 0; jp < 4; ++jp)
            q[pl * 4 + jp] = aload(rdb + pl * 256 + jp * 16);
}
__device__ __forceinline__ bool tagok(const u64* q, unsigned tag) {
    unsigned acc = 0;
    #pragma unroll
    for (int i = 0; i < 32; ++i) {
        acc |= ((unsigned)q[i] ^ tag) & 0xFFFFu;
        acc |= ((unsigned)(q[i] >> 32) ^ tag) & 0xFFFFu;
    }
    return acc == 0u;
}
__device__ __forceinline__ bf16x8 unpk(const u64* qq) {   // &q[pl*4]
    us8 u;
    u[0] = (unsigned short)(qq[0] >> 16); u[1] = (unsigned short)(qq[0] >> 48);
    u[2] = (unsigned short)(qq[1] >> 16); u[3] = (unsigned short)(qq[1] >> 48);
    u[4] = (unsigned short)(qq[2] >> 16); u[5] = (unsigned short)(qq[2] >> 48);
    u[6] = (unsigned short)(qq[3] >> 16); u[7] = (unsigned short)(qq[3] >> 48);
    return __builtin_bit_cast(bf16x8, u);
}

__global__ __launch_bounds__(NTHR)
void lstm_w4(const float* __restrict__ x,    // (B,S,F)
             const float* __restrict__ fw,   // (F)
             const float* __restrict__ tw,   // (S)
             const float* __restrict__ Wih,  // (L,3H,F)
             const float* __restrict__ bih,  // (L,3H)
             const float* __restrict__ Whh,  // (L,3H,H)
             const float* __restrict__ bhh,  // (L,3H)
             float* __restrict__ out,        // outputs | hs | cs
             void* __restrict__ ws)
{
    __shared__ unsigned short sW[3 * 16 * 64 * 8];   // 48 KB, frag-ordered bf16

    unsigned* prog = (unsigned*)ws;                   // prog[(bg*2+nt)*16 + ug*2+uh]
    u64* h0buf = (u64*)((char*)ws + 4096);            // [8][bg] slabs
    u64* h1buf = h0buf + H0_U64;                      // [2][bg] slabs
    float* outputs = out;
    float* hs = out + (size_t)B_ * S_ * H_;
    float* cs = hs + (size_t)2 * B_ * H_;

    const int bid   = blockIdx.x;
    const int lane  = threadIdx.x;
    const int ntw   = bid & 1;
    const int uh    = (bid >> 1) & 1;
    const int bg    = (bid >> 2) & 3;
    const int ug    = (bid >> 4) & 7;
    const int layer = (bid >> 7) & 1;

    const float* Wih_l = Wih + (size_t)layer * G3 * F_;
    const float* Whh_l = Whh + (size_t)layer * G3 * H_;

    // ---- stage this wave's weights: 3 gates x 16 units x K=512 (fw folded) ----
    // A-frag (16x16x32): lane holds A[(l&15)][(l>>4)*8 + j] of tile (gate,kt)
    for (int idx = lane; idx < 3 * 16 * 64; idx += NTHR) {
        const int l  = idx & 63;
        const int kt = (idx >> 6) & 15;
        const int g  = idx >> 10;
        const int grow = g * H_ + ug * 32 + uh * 16 + (l & 15);
        const int k = kt * 32 + (l >> 4) * 8;
        float4 a, b;
        if (k < 256) {
            const float* s = Wih_l + (size_t)grow * F_ + k;
            a = *(const float4*)s; b = *(const float4*)(s + 4);
            if (layer == 0) {   // fold features_weighting into W_ih
                const float4 wa = *(const float4*)(fw + k);
                const float4 wb = *(const float4*)(fw + k + 4);
                a.x *= wa.x; a.y *= wa.y; a.z *= wa.z; a.w *= wa.w;
                b.x *= wb.x; b.y *= wb.y; b.z *= wb.z; b.w *= wb.w;
            }
        } else {
            const float* s = Whh_l + (size_t)grow * H_ + (k - 256);
            a = *(const float4*)s; b = *(const float4*)(s + 4);
        }
        us8 w;
        w[0] = f2bf(a.x); w[1] = f2bf(a.y); w[2] = f2bf(a.z); w[3] = f2bf(a.w);
        w[4] = f2bf(b.x); w[5] = f2bf(b.y); w[6] = f2bf(b.z); w[7] = f2bf(b.w);
        *(us8*)&sW[(size_t)idx * 8] = w;
    }
    __syncthreads();

    float bia[3][4];
    #pragma unroll
    for (int r = 0; r < 4; ++r) {
        const int gu = ug * 32 + uh * 16 + (lane >> 4) * 4 + r;
        #pragma unroll
        for (int s = 0; s < 3; ++s)
            bia[s][r] = bih[layer * G3 + s * H_ + gu] + bhh[layer * G3 + s * H_ + gu];
    }

    const int ul0  = uh * 16 + (lane >> 4) * 4;       // unit base (mult of 4)
    const int hg0  = ug * 32 + ul0;
    const int bcol = bg * 32 + ntw * 16 + (lane & 15);
    // producer slab offset (u64): nt, pl=ug, hi=ul0>>3, jp0=(ul0&7)>>1, col
    const size_t wofs = (size_t)ntw * 2048 + (size_t)ug * 256
                      + (size_t)(uh * 2 + ((lane >> 4) >> 1)) * 64
                      + (size_t)(((lane >> 4) & 1) * 2) * 16 + (lane & 15);
    // consumer per-lane base: nt, hi=lane>>4, col=lane&15
    const size_t rofs = (size_t)ntw * 2048 + (size_t)(lane >> 4) * 64 + (lane & 15);
    const int dom = bg * 2 + ntw;                     // sync domain (bg, nt)

    float c_reg[4] = {0.f, 0.f, 0.f, 0.f};

    #define WAf(g, kt) (*(const bf16x8*)&sW[(size_t)(((g) * 16 + (kt)) * 64 + lane) * 8])

    if (layer == 0) {
        float4 xf[16];
        #pragma unroll
        for (int kt = 0; kt < 8; ++kt) {   // prefetch x(0)
            const float* s = x + ((size_t)bcol * S_ + 0) * F_ + kt * 32 + (lane >> 4) * 8;
            xf[2 * kt] = *(const float4*)s; xf[2 * kt + 1] = *(const float4*)(s + 4);
        }
        float twc = tw[0], twn = tw[1];
        unsigned prog_min = 0;             // cached wave-min of consumer progress

        for (int p = 0; p < S_; ++p) {
            const u64* rdb = h0buf + (size_t)(((p - 1) & 7) * BGROUPS + bg) * SLAB_U64 + rofs;
            u64 q[32];
            loadq(rdb, q);                 // h0(p-1) polls fly under x work

            bf16x8 xb[8];                  // convert prefetched x(p)
            #pragma unroll
            for (int kt = 0; kt < 8; ++kt) {
                const float4 a = xf[2 * kt], b = xf[2 * kt + 1];
                us8 w;
                w[0] = f2bf(a.x); w[1] = f2bf(a.y); w[2] = f2bf(a.z); w[3] = f2bf(a.w);
                w[4] = f2bf(b.x); w[5] = f2bf(b.y); w[6] = f2bf(b.z); w[7] = f2bf(b.w);
                xb[kt] = __builtin_bit_cast(bf16x8, w);
            }
            if (p + 1 < S_) {              // prefetch x(p+1)
                #pragma unroll
                for (int kt = 0; kt < 8; ++kt) {
                    const float* s = x + ((size_t)bcol * S_ + (p + 1)) * F_
                                   + kt * 32 + (lane >> 4) * 8;
                    xf[2 * kt] = *(const float4*)s; xf[2 * kt + 1] = *(const float4*)(s + 4);
                }
            }

            f32x4 ai = {0.f, 0.f, 0.f, 0.f}, ag = ai, ao = ai;
            #pragma unroll
            for (int kt = 0; kt < 8; ++kt) {
                ai = MF(WAf(0, kt), xb[kt], ai);
                ag = MF(WAf(1, kt), xb[kt], ag);
                ao = MF(WAf(2, kt), xb[kt], ao);
            }
            #pragma unroll
            for (int r = 0; r < 4; ++r) {  // times_weighting as post-GEMM scalar
                ai[r] *= twc; ag[r] *= twc; ao[r] *= twc;
            }

            while (!__all(tagok(q, (unsigned)p))) loadq(rdb, q);
            #pragma unroll
            for (int pl = 0; pl < 8; ++pl) {
                const bf16x8 hb = unpk(&q[pl * 4]);
                ai = MF(WAf(0, 8 + pl), hb, ai);
                ag = MF(WAf(1, 8 + pl), hb, ag);
                ao = MF(WAf(2, 8 + pl), hb, ao);
            }

            // back-pressure: overwriting slab p&7 (tag p-7) needs layer1 >= p-7.
            // CACHED: re-read prog only when the cached wave-min can't prove slack.
            if (p >= H0_DEPTH && prog_min < (unsigned)(p - (H0_DEPTH - 1))) {
                const unsigned need = (unsigned)(p - (H0_DEPTH - 1));
                unsigned mv;
                do {
                    unsigned pv = (lane < 16)
                        ? aload32(&prog[dom * 16 + lane]) : 0xFFFFFFFFu;
                    #pragma unroll
                    for (int o = 1; o < 16; o <<= 1)
                        pv = min(pv, (unsigned)__shfl_xor((int)pv, o));
                    mv = (unsigned)__shfl((int)pv, 0);
                } while (mv < need);
                prog_min = mv;
            }

            u64* wb = h0buf + (size_t)((p & 7) * BGROUPS + bg) * SLAB_U64 + wofs;
            const unsigned tagv = (unsigned)(p + 1);
            float hnv[4], cnv[4];
            unsigned er[4];
            #pragma unroll
            for (int r = 0; r < 4; ++r) {
                const float gi = ai[r] + bia[0][r];
                const float gg = ag[r] + bia[1][r];
                const float go = ao[r] + bia[2][r];
                const float cp = c_reg[r];
                const float fg = sigf(cp);                 // forget = sigmoid(c_prev)
                const float cn = fg * cp + sigf(gi) * tanh_fast(gg);
                const float hn = sigf(go) * tanh_fast(cn);
                c_reg[r] = cn; hnv[r] = hn; cnv[r] = cn;
                er[r] = ((unsigned)f2bf(hn) << 16) | tagv;
            }
            astore(wb,      er[0] | ((u64)er[1] << 32));
            astore(wb + 16, er[2] | ((u64)er[3] << 32));

            if (p == S_ - 1) {
                *(float4*)(hs + (size_t)bcol * H_ + hg0) =
                    make_float4(hnv[0], hnv[1], hnv[2], hnv[3]);
                *(float4*)(cs + (size_t)bcol * H_ + hg0) =
                    make_float4(cnv[0], cnv[1], cnv[2], cnv[3]);
            }
            twc = twn;
            if (p + 2 < S_) twn = tw[p + 2];
        }
    } else {
        for (int p = 1; p <= S_; ++p) {
            const int t = p - 1;
            const u64* rd0 = h0buf + (size_t)(((p - 1) & 7) * BGROUPS + bg) * SLAB_U64 + rofs;
            const u64* rd1 = h1buf + (size_t)(((p - 2) & 1) * BGROUPS + bg) * SLAB_U64 + rofs;
            u64 q0[32], q1[32];
            loadq(rd0, q0);
            loadq(rd1, q1);                // both flights overlap

            while (!__all(tagok(q0, (unsigned)p))) loadq(rd0, q0);
            if (lane == 0)                 // publish h0(p-1) consumption
                astore32(&prog[dom * 16 + ug * 2 + uh], (unsigned)p);

            f32x4 ai = {0.f, 0.f, 0.f, 0.f}, ag = ai, ao = ai;
            #pragma unroll
            for (int pl = 0; pl < 8; ++pl) {
                const bf16x8 hb = unpk(&q0[pl * 4]);
                ai = MF(WAf(0, pl), hb, ai);
                ag = MF(WAf(1, pl), hb, ag);
                ao = MF(WAf(2, pl), hb, ao);
            }

            while (!__all(tagok(q1, (unsigned)(p - 1)))) loadq(rd1, q1);
            #pragma unroll
            for (int pl = 0; pl < 8; ++pl) {
                const bf16x8 hb = unpk(&q1[pl * 4]);
                ai = MF(WAf(0, 8 + pl), hb, ai);
                ag = MF(WAf(1, 8 + pl), hb, ag);
                ao = MF(WAf(2, 8 + pl), hb, ao);
            }

            u64* wb = h1buf + (size_t)(((p - 1) & 1) * BGROUPS + bg) * SLAB_U64 + wofs;
            const unsigned tagv = (unsigned)p;
            float hnv[4], cnv[4];
            unsigned er[4];
            #pragma unroll
            for (int r = 0; r < 4; ++r) {
                const float gi = ai[r] + bia[0][r];
                const float gg = ag[r] + bia[1][r];
                const float go = ao[r] + bia[2][r];
                const float cp = c_reg[r];
                const float fg = sigf(cp);                 // forget = sigmoid(c_prev)
                const float cn = fg * cp + sigf(gi) * tanh_fast(gg);
                const float hn = sigf(go) * tanh_fast(cn);
                c_reg[r] = cn; hnv[r] = hn; cnv[r] = cn;
                er[r] = ((unsigned)f2bf(hn) << 16) | tagv;
            }
            astore(wb,      er[0] | ((u64)er[1] << 32));
            astore(wb + 16, er[2] | ((u64)er[3] << 32));

            *(float4*)(outputs + ((size_t)bcol * S_ + t) * H_ + hg0) =
                make_float4(hnv[0], hnv[1], hnv[2], hnv[3]);
            if (p == S_) {
                *(float4*)(hs + (size_t)B_ * H_ + (size_t)bcol * H_ + hg0) =
                    make_float4(hnv[0], hnv[1], hnv[2], hnv[3]);
                *(float4*)(cs + (size_t)B_ * H_ + (size_t)bcol * H_ + hg0) =
                    make_float4(cnv[0], cnv[1], cnv[2], cnv[3]);
            }
        }
    }
}

extern "C" void kernel_launch(void* const* d_in, const int* in_sizes, int n_in,
                              void* d_out, int out_size, void* d_ws, size_t ws_size,
                              hipStream_t stream) {
    const float* x   = (const float*)d_in[0];
    const float* fw  = (const float*)d_in[1];
    const float* tw  = (const float*)d_in[2];
    const float* Wih = (const float*)d_in[3];
    const float* bih = (const float*)d_in[4];
    const float* Whh = (const float*)d_in[5];
    const float* bhh = (const float*)d_in[6];
    float* out = (float*)d_out;

    // zero prog + tagged slabs each call (tag 0 == valid h(-1)=0); 1.28 MB
    hipMemsetAsync(d_ws, 0, WS_ZERO_BYTES, stream);

    void* kargs[] = { (void*)&x, (void*)&fw, (void*)&tw, (void*)&Wih, (void*)&bih,
                      (void*)&Whh, (void*)&bhh, (void*)&out, (void*)&d_ws };
    hipError_t e = hipLaunchCooperativeKernel((const void*)lstm_w4,
                                              dim3(NBLK), dim3(NTHR),
                                              kargs, 0, stream);
    if (e != hipSuccess) {
        // fallback: plain launch; 256 blocks x 48KB LDS x 64 thr -> >=1/CU on
        // 256 CUs, trivially co-resident; only device-scope atomics used.
        lstm_w4<<<dim3(NBLK), dim3(NTHR), 0, stream>>>(
            x, fw, tw, Wih, bih, Whh, bhh, out, d_ws);
    }
}